// Round 3
// baseline (1498.538 us; speedup 1.0000x reference)
//
#include <hip/hip_runtime.h>
#include <hip/hip_bf16.h>

#define CH 64
#define RPB 128      // rows per bucket
#define RPB_SH 7
#define NBLK 512     // count/fill blocks
#define MAXNB 800    // max buckets supported by LDS arrays
#define SCAN_B 512

// ---------------------------------------------------------------------------
// Kernel 1: fused dual GEMM.  xw = x @ w_conv (ws), out = x @ w_lin (acc init)
// ---------------------------------------------------------------------------
__global__ __launch_bounds__(256) void gemm2_kernel(
    const float* __restrict__ x, const float* __restrict__ wc,
    const float* __restrict__ wl, float* __restrict__ xw,
    float* __restrict__ acc, int n) {
  __shared__ float swc[CH * CH];
  __shared__ float swl[CH * CH];
  for (int i = threadIdx.x; i < CH * CH; i += 256) {
    swc[i] = wc[i];
    swl[i] = wl[i];
  }
  __syncthreads();
  const int lane = threadIdx.x & 63;
  const int wrow = threadIdx.x >> 6;
  for (int row = blockIdx.x * 4 + wrow; row < n; row += gridDim.x * 4) {
    const float xv = x[row * CH + lane];
    float a1 = 0.f, a2 = 0.f;
#pragma unroll
    for (int k = 0; k < CH; ++k) {
      const float xk = __shfl(xv, k, 64);
      a1 = fmaf(xk, swc[k * CH + lane], a1);
      a2 = fmaf(xk, swl[k * CH + lane], a2);
    }
    xw[row * CH + lane] = a1;
    acc[row * CH + lane] = a2;
  }
}

// ---------------------------------------------------------------------------
// Phase A: per-(bucket, block) edge counts via LDS histogram. No global atomics.
// countsT[b*NBLK + blk] = #edges in block blk's chunk with row in bucket b.
// ---------------------------------------------------------------------------
__global__ __launch_bounds__(256) void countT_kernel(
    const int* __restrict__ r1, const int* __restrict__ r2,
    int* __restrict__ countsT, int nnz, int nb) {
  __shared__ int h[MAXNB];
  for (int i = threadIdx.x; i < nb; i += 256) h[i] = 0;
  __syncthreads();
  const int tot = 2 * nnz;
  const int chunk = (tot + NBLK - 1) / NBLK;
  const int e0 = blockIdx.x * chunk;
  const int e1 = min(tot, e0 + chunk);
  for (int e = e0 + threadIdx.x; e < e1; e += 256) {
    const int r = (e < nnz) ? r1[e] : r2[e - nnz];
    atomicAdd(&h[r >> RPB_SH], 1);
  }
  __syncthreads();
  for (int b = threadIdx.x; b < nb; b += 256)
    countsT[b * NBLK + blockIdx.x] = h[b];
}

// ---------------------------------------------------------------------------
// Phase B: exclusive scan of countsT (length nb*NBLK), in place, 3 kernels.
// ---------------------------------------------------------------------------
__global__ __launch_bounds__(SCAN_B) void scan_partial(
    const int* __restrict__ in, int* __restrict__ partials, int n) {
  __shared__ int s[SCAN_B];
  const int i = blockIdx.x * SCAN_B + threadIdx.x;
  s[threadIdx.x] = (i < n) ? in[i] : 0;
  __syncthreads();
  for (int off = SCAN_B / 2; off > 0; off >>= 1) {
    if (threadIdx.x < off) s[threadIdx.x] += s[threadIdx.x + off];
    __syncthreads();
  }
  if (threadIdx.x == 0) partials[blockIdx.x] = s[0];
}

__global__ __launch_bounds__(1024) void scan_partials_scan(
    int* __restrict__ partials, int nb) {
  __shared__ int s[1024];
  const int v = (threadIdx.x < nb) ? partials[threadIdx.x] : 0;
  s[threadIdx.x] = v;
  __syncthreads();
  for (int off = 1; off < 1024; off <<= 1) {
    const int t = (threadIdx.x >= off) ? s[threadIdx.x - off] : 0;
    __syncthreads();
    s[threadIdx.x] += t;
    __syncthreads();
  }
  if (threadIdx.x < nb) partials[threadIdx.x] = s[threadIdx.x] - v;  // exclusive
}

__global__ __launch_bounds__(SCAN_B) void scan_final(
    int* __restrict__ data, const int* __restrict__ partials, int n) {
  __shared__ int s[SCAN_B];
  const int i = blockIdx.x * SCAN_B + threadIdx.x;
  const int v = (i < n) ? data[i] : 0;
  s[threadIdx.x] = v;
  __syncthreads();
  for (int off = 1; off < SCAN_B; off <<= 1) {
    const int t = (threadIdx.x >= off) ? s[threadIdx.x - off] : 0;
    __syncthreads();
    s[threadIdx.x] += t;
    __syncthreads();
  }
  if (i < n) data[i] = s[threadIdx.x] - v + partials[blockIdx.x];  // exclusive
}

// ---------------------------------------------------------------------------
// Phase C: fill bucketed edge records. LDS cursors only (block-private runs).
// record = ((row & 127) << 17) | col  (col < 2^17), val bits in .y
// ---------------------------------------------------------------------------
__global__ __launch_bounds__(256) void fillB_kernel(
    const int* __restrict__ r1, const int* __restrict__ c1, const float* __restrict__ v1,
    const int* __restrict__ r2, const int* __restrict__ c2, const float* __restrict__ v2,
    const int* __restrict__ soff, int2* __restrict__ ebuf, int nnz, int nb) {
  __shared__ int cur[MAXNB];
  for (int b = threadIdx.x; b < nb; b += 256)
    cur[b] = soff[b * NBLK + blockIdx.x];
  __syncthreads();
  const int tot = 2 * nnz;
  const int chunk = (tot + NBLK - 1) / NBLK;
  const int e0 = blockIdx.x * chunk;
  const int e1 = min(tot, e0 + chunk);
  for (int e = e0 + threadIdx.x; e < e1; e += 256) {
    int r, c;
    float v;
    if (e < nnz) {
      r = r1[e]; c = c1[e]; v = v1[e];
    } else {
      r = r2[e - nnz]; c = c2[e - nnz]; v = v2[e - nnz];
    }
    const int b = r >> RPB_SH;
    const int slot = atomicAdd(&cur[b], 1);
    ebuf[slot] = make_int2(((r & (RPB - 1)) << 17) | c, __float_as_int(v));
  }
}

// ---------------------------------------------------------------------------
// Phase D: per-bucket gather-accumulate in LDS; fused linear term + sigmoid.
// One block per bucket; wave processes one record at a time (64 channels).
// ---------------------------------------------------------------------------
__global__ __launch_bounds__(256) void bucket_gather_kernel(
    const int* __restrict__ soff, const int2* __restrict__ ebuf,
    const float* __restrict__ xw, float* __restrict__ out,
    int n, int nb, int tot) {
  __shared__ float acc[RPB * CH];  // 32 KB
  for (int i = threadIdx.x; i < RPB * CH; i += 256) acc[i] = 0.f;
  __syncthreads();
  const int b = blockIdx.x;
  const int beg = soff[b * NBLK];
  const int end = (b + 1 < nb) ? soff[(b + 1) * NBLK] : tot;
  const int lane = threadIdx.x & 63;
  const int wv = threadIdx.x >> 6;

  for (int base = beg + wv * 64; base < end; base += 256) {
    const int m = min(64, end - base);
    const int2 rec = ebuf[base + ((lane < m) ? lane : 0)];
    int i = 0;
    for (; i + 8 <= m; i += 8) {
      float xv[8], vv[8];
      int lr[8];
#pragma unroll
      for (int j = 0; j < 8; ++j) {
        const int packed = __builtin_amdgcn_readlane(rec.x, i + j);
        vv[j] = __int_as_float(__builtin_amdgcn_readlane(rec.y, i + j));
        lr[j] = packed >> 17;
        xv[j] = xw[(packed & 0x1FFFF) * CH + lane];
      }
#pragma unroll
      for (int j = 0; j < 8; ++j)
        atomicAdd(&acc[lr[j] * CH + lane], vv[j] * xv[j]);
    }
    for (; i < m; ++i) {
      const int packed = __builtin_amdgcn_readlane(rec.x, i);
      const float v = __int_as_float(__builtin_amdgcn_readlane(rec.y, i));
      const float xv0 = xw[(packed & 0x1FFFF) * CH + lane];
      atomicAdd(&acc[(packed >> 17) * CH + lane], v * xv0);
    }
  }
  __syncthreads();
  // epilogue: out = sigmoid(linear + acc), rows b*RPB .. b*RPB+127
  const int base_idx = b * RPB * CH;
  for (int i = threadIdx.x; i < RPB * CH; i += 256) {
    const int idx = base_idx + i;
    if (idx < n * CH) {
      const float s = out[idx] + acc[i];
      out[idx] = 1.f / (1.f + __expf(-s));
    }
  }
}

// ---------------------------------------------------------------------------
// Fallback path (ws too small): atomic scatter + sigmoid.
// ---------------------------------------------------------------------------
__global__ __launch_bounds__(256) void scatter_kernel(
    const int* __restrict__ rows, const int* __restrict__ cols,
    const float* __restrict__ vals, const float* __restrict__ xw,
    float* __restrict__ out, int nnz) {
  const int lane = threadIdx.x & 63;
  const int wid = (blockIdx.x * blockDim.x + threadIdx.x) >> 6;
  const int nwaves = (gridDim.x * blockDim.x) >> 6;
  for (int k = wid; k < nnz; k += nwaves) {
    const float xv = xw[cols[k] * CH + lane];
    atomicAdd(&out[rows[k] * CH + lane], vals[k] * xv);
  }
}

__global__ __launch_bounds__(256) void sigmoid_kernel(float* __restrict__ out, int n4) {
  const int i = blockIdx.x * blockDim.x + threadIdx.x;
  if (i < n4) {
    float4 v = reinterpret_cast<float4*>(out)[i];
    v.x = 1.f / (1.f + __expf(-v.x));
    v.y = 1.f / (1.f + __expf(-v.y));
    v.z = 1.f / (1.f + __expf(-v.z));
    v.w = 1.f / (1.f + __expf(-v.w));
    reinterpret_cast<float4*>(out)[i] = v;
  }
}

extern "C" void kernel_launch(void* const* d_in, const int* in_sizes, int n_in,
                              void* d_out, int out_size, void* d_ws, size_t ws_size,
                              hipStream_t stream) {
  const float* x         = (const float*)d_in[0];
  const int*   down_rows = (const int*)d_in[1];
  const int*   down_cols = (const int*)d_in[2];
  const float* down_vals = (const float*)d_in[3];
  const int*   up_rows   = (const int*)d_in[4];
  const int*   up_cols   = (const int*)d_in[5];
  const float* up_vals   = (const float*)d_in[6];
  const float* w_conv    = (const float*)d_in[7];
  const float* w_lin     = (const float*)d_in[8];

  const int n   = in_sizes[0] / CH;  // 100000
  const int nnz = in_sizes[1];       // 1600000
  const int tot = 2 * nnz;
  const int nb  = (n + RPB - 1) / RPB;  // 782

  float* out = (float*)d_out;

  // ws layout
  float* xw      = (float*)d_ws;                      // n*CH
  int*   soff    = (int*)(xw + (size_t)n * CH);       // nb*NBLK (counts -> scan, in place)
  int*   partial = soff + (size_t)nb * NBLK;          // 1024
  int2*  ebuf    = (int2*)(partial + 1024);           // tot records (8B each)
  const size_t need =
      ((size_t)n * CH + (size_t)nb * NBLK + 1024) * 4 + (size_t)tot * 8;

  // xw = x@w_conv (ws), out = x@w_lin (accumulator)
  gemm2_kernel<<<4096, 256, 0, stream>>>(x, w_conv, w_lin, xw, out, n);

  if (ws_size >= need && nb <= MAXNB && n < (1 << 17)) {
    // A: counts
    countT_kernel<<<NBLK, 256, 0, stream>>>(down_rows, up_rows, soff, nnz, nb);
    // B: exclusive scan of nb*NBLK counts (in place)
    const int ntot = nb * NBLK;
    const int nsb = (ntot + SCAN_B - 1) / SCAN_B;  // <= 1024 required
    scan_partial<<<nsb, SCAN_B, 0, stream>>>(soff, partial, ntot);
    scan_partials_scan<<<1, 1024, 0, stream>>>(partial, nsb);
    scan_final<<<nsb, SCAN_B, 0, stream>>>(soff, partial, ntot);
    // C: bucketed fill
    fillB_kernel<<<NBLK, 256, 0, stream>>>(down_rows, down_cols, down_vals,
                                           up_rows, up_cols, up_vals,
                                           soff, ebuf, nnz, nb);
    // D: per-bucket gather + fused sigmoid
    bucket_gather_kernel<<<nb, 256, 0, stream>>>(soff, ebuf, xw, out, n, nb, tot);
  } else {
    scatter_kernel<<<4096, 256, 0, stream>>>(down_rows, down_cols, down_vals, xw, out, nnz);
    scatter_kernel<<<4096, 256, 0, stream>>>(up_rows, up_cols, up_vals, xw, out, nnz);
    const int n4 = (n * CH) / 4;
    sigmoid_kernel<<<(n4 + 255) / 256, 256, 0, stream>>>(out, n4);
  }
}

// Round 4
// 304.137 us; speedup vs baseline: 4.9272x; 4.9272x over previous
//
#include <hip/hip_runtime.h>
#include <hip/hip_bf16.h>

#define CH 64
#define RPB 128      // rows per bucket
#define RPB_SH 7
#define NBLK 512     // count/fill blocks
#define MAXNB 800    // max buckets supported by LDS arrays
#define SCAN_B 512
#define CAP 6144     // max records per bucket for in-LDS sort (mean 4096, sigma 64)

// ---------------------------------------------------------------------------
// Kernel 1: fused dual GEMM.  xw = x @ w_conv (ws), out = x @ w_lin (acc init)
// ---------------------------------------------------------------------------
__global__ __launch_bounds__(256) void gemm2_kernel(
    const float* __restrict__ x, const float* __restrict__ wc,
    const float* __restrict__ wl, float* __restrict__ xw,
    float* __restrict__ acc, int n) {
  __shared__ float swc[CH * CH];
  __shared__ float swl[CH * CH];
  for (int i = threadIdx.x; i < CH * CH; i += 256) {
    swc[i] = wc[i];
    swl[i] = wl[i];
  }
  __syncthreads();
  const int lane = threadIdx.x & 63;
  const int wrow = threadIdx.x >> 6;
  for (int row = blockIdx.x * 4 + wrow; row < n; row += gridDim.x * 4) {
    const float xv = x[row * CH + lane];
    float a1 = 0.f, a2 = 0.f;
#pragma unroll
    for (int k = 0; k < CH; ++k) {
      const float xk = __shfl(xv, k, 64);
      a1 = fmaf(xk, swc[k * CH + lane], a1);
      a2 = fmaf(xk, swl[k * CH + lane], a2);
    }
    xw[row * CH + lane] = a1;
    acc[row * CH + lane] = a2;
  }
}

// ---------------------------------------------------------------------------
// Phase A: per-(bucket, block) edge counts via LDS histogram. No global atomics.
// ---------------------------------------------------------------------------
__global__ __launch_bounds__(256) void countT_kernel(
    const int* __restrict__ r1, const int* __restrict__ r2,
    int* __restrict__ countsT, int nnz, int nb) {
  __shared__ int h[MAXNB];
  for (int i = threadIdx.x; i < nb; i += 256) h[i] = 0;
  __syncthreads();
  const int tot = 2 * nnz;
  const int chunk = (tot + NBLK - 1) / NBLK;
  const int e0 = blockIdx.x * chunk;
  const int e1 = min(tot, e0 + chunk);
  for (int e = e0 + threadIdx.x; e < e1; e += 256) {
    const int r = (e < nnz) ? r1[e] : r2[e - nnz];
    atomicAdd(&h[r >> RPB_SH], 1);
  }
  __syncthreads();
  for (int b = threadIdx.x; b < nb; b += 256)
    countsT[b * NBLK + blockIdx.x] = h[b];
}

// ---------------------------------------------------------------------------
// Phase B: exclusive scan of countsT (length nb*NBLK), in place, 3 kernels.
// ---------------------------------------------------------------------------
__global__ __launch_bounds__(SCAN_B) void scan_partial(
    const int* __restrict__ in, int* __restrict__ partials, int n) {
  __shared__ int s[SCAN_B];
  const int i = blockIdx.x * SCAN_B + threadIdx.x;
  s[threadIdx.x] = (i < n) ? in[i] : 0;
  __syncthreads();
  for (int off = SCAN_B / 2; off > 0; off >>= 1) {
    if (threadIdx.x < off) s[threadIdx.x] += s[threadIdx.x + off];
    __syncthreads();
  }
  if (threadIdx.x == 0) partials[blockIdx.x] = s[0];
}

__global__ __launch_bounds__(1024) void scan_partials_scan(
    int* __restrict__ partials, int nb) {
  __shared__ int s[1024];
  const int v = (threadIdx.x < nb) ? partials[threadIdx.x] : 0;
  s[threadIdx.x] = v;
  __syncthreads();
  for (int off = 1; off < 1024; off <<= 1) {
    const int t = (threadIdx.x >= off) ? s[threadIdx.x - off] : 0;
    __syncthreads();
    s[threadIdx.x] += t;
    __syncthreads();
  }
  if (threadIdx.x < nb) partials[threadIdx.x] = s[threadIdx.x] - v;  // exclusive
}

__global__ __launch_bounds__(SCAN_B) void scan_final(
    int* __restrict__ data, const int* __restrict__ partials, int n) {
  __shared__ int s[SCAN_B];
  const int i = blockIdx.x * SCAN_B + threadIdx.x;
  const int v = (i < n) ? data[i] : 0;
  s[threadIdx.x] = v;
  __syncthreads();
  for (int off = 1; off < SCAN_B; off <<= 1) {
    const int t = (threadIdx.x >= off) ? s[threadIdx.x - off] : 0;
    __syncthreads();
    s[threadIdx.x] += t;
    __syncthreads();
  }
  if (i < n) data[i] = s[threadIdx.x] - v + partials[blockIdx.x];  // exclusive
}

// ---------------------------------------------------------------------------
// Phase C: fill bucketed edge records. LDS cursors only (block-private runs).
// record.x = ((row & 127) << 17) | col   (col < 2^17), record.y = val bits
// ---------------------------------------------------------------------------
__global__ __launch_bounds__(256) void fillB_kernel(
    const int* __restrict__ r1, const int* __restrict__ c1, const float* __restrict__ v1,
    const int* __restrict__ r2, const int* __restrict__ c2, const float* __restrict__ v2,
    const int* __restrict__ soff, int2* __restrict__ ebuf, int nnz, int nb) {
  __shared__ int cur[MAXNB];
  for (int b = threadIdx.x; b < nb; b += 256)
    cur[b] = soff[b * NBLK + blockIdx.x];
  __syncthreads();
  const int tot = 2 * nnz;
  const int chunk = (tot + NBLK - 1) / NBLK;
  const int e0 = blockIdx.x * chunk;
  const int e1 = min(tot, e0 + chunk);
  for (int e = e0 + threadIdx.x; e < e1; e += 256) {
    int r, c;
    float v;
    if (e < nnz) {
      r = r1[e]; c = c1[e]; v = v1[e];
    } else {
      r = r2[e - nnz]; c = c2[e - nnz]; v = v2[e - nnz];
    }
    const int b = r >> RPB_SH;
    const int slot = atomicAdd(&cur[b], 1);
    ebuf[slot] = make_int2(((r & (RPB - 1)) << 17) | c, __float_as_int(v));
  }
}

// ---------------------------------------------------------------------------
// Phase D: in-bucket counting sort (one block per bucket), in place via LDS
// staging. Emits row_ptr. No global atomics; output writes are L2-local.
// ---------------------------------------------------------------------------
__global__ __launch_bounds__(256) void sortB_kernel(
    const int* __restrict__ soff, int2* __restrict__ ebuf,
    int* __restrict__ row_ptr, int* __restrict__ bflag,
    int n, int nb, int tot) {
  __shared__ int2 raw[CAP];   // 48 KB
  __shared__ int hist[RPB];
  __shared__ int sc[RPB];
  __shared__ int cur[RPB];
  const int b = blockIdx.x;
  const int beg = soff[b * NBLK];
  const int end = (b + 1 < nb) ? soff[(b + 1) * NBLK] : tot;
  const int cnt = end - beg;

  if (b == nb - 1 && threadIdx.x == 0) row_ptr[n] = tot;

  if (cnt > CAP) {  // degenerate distribution: leave unsorted, flag for gather
    if (threadIdx.x == 0) bflag[b] = 1;
    const int r0 = b * RPB;
    for (int r = threadIdx.x; r < RPB; r += 256) {
      const int gr = r0 + r;
      if (gr < n) row_ptr[gr] = beg;
    }
    return;
  }
  if (threadIdx.x == 0) bflag[b] = 0;
  if (threadIdx.x < RPB) hist[threadIdx.x] = 0;
  __syncthreads();

  for (int i = threadIdx.x; i < cnt; i += 256) {
    const int2 rec = ebuf[beg + i];
    raw[i] = rec;
    atomicAdd(&hist[rec.x >> 17], 1);
  }
  __syncthreads();

  // exclusive scan of hist[128] (Hillis-Steele on first 128 threads)
  int v = 0;
  if (threadIdx.x < RPB) {
    v = hist[threadIdx.x];
    sc[threadIdx.x] = v;
  }
  __syncthreads();
  for (int off = 1; off < RPB; off <<= 1) {
    int t = 0;
    if (threadIdx.x < RPB && threadIdx.x >= off) t = sc[threadIdx.x - off];
    __syncthreads();
    if (threadIdx.x < RPB) sc[threadIdx.x] += t;
    __syncthreads();
  }
  if (threadIdx.x < RPB) {
    const int ex = sc[threadIdx.x] - v;
    cur[threadIdx.x] = ex;
    const int gr = b * RPB + threadIdx.x;
    if (gr < n) row_ptr[gr] = beg + ex;
  }
  __syncthreads();

  for (int i = threadIdx.x; i < cnt; i += 256) {
    const int2 rec = raw[i];
    const int pos = atomicAdd(&cur[rec.x >> 17], 1);
    ebuf[beg + pos] = rec;
  }
}

// ---------------------------------------------------------------------------
// Phase E: row gather — one wave per row, register accumulate, fused sigmoid.
// out[] already holds the x@w_lin term.
// ---------------------------------------------------------------------------
__global__ __launch_bounds__(256) void gather_kernel(
    const int* __restrict__ row_ptr, const int* __restrict__ soff,
    const int* __restrict__ bflag, const int2* __restrict__ ebuf,
    const float* __restrict__ xw, float* __restrict__ out,
    int n, int nb, int tot) {
  const int lane = threadIdx.x & 63;
  const int w = (blockIdx.x * blockDim.x + threadIdx.x) >> 6;
  const int nw = (gridDim.x * blockDim.x) >> 6;
  for (int row = w; row < n; row += nw) {
    float acc = out[row * CH + lane];  // linear term
    const int b = row >> RPB_SH;
    if (bflag[b]) {  // unsorted bucket: predicated scan of whole bucket
      const int bb = soff[b * NBLK];
      const int be = (b + 1 < nb) ? soff[(b + 1) * NBLK] : tot;
      const int rl = row & (RPB - 1);
      for (int e = bb; e < be; ++e) {
        const int2 rec = ebuf[e];
        if ((rec.x >> 17) == rl)
          acc = fmaf(__int_as_float(rec.y), xw[(rec.x & 0x1FFFF) * CH + lane], acc);
      }
    } else {
      const int beg = row_ptr[row];
      const int end = row_ptr[row + 1];
      int e = beg;
      for (; e + 4 <= end; e += 4) {
        const int2 r0 = ebuf[e], r1 = ebuf[e + 1], r2 = ebuf[e + 2], r3 = ebuf[e + 3];
        const float x0 = xw[(r0.x & 0x1FFFF) * CH + lane];
        const float x1 = xw[(r1.x & 0x1FFFF) * CH + lane];
        const float x2 = xw[(r2.x & 0x1FFFF) * CH + lane];
        const float x3 = xw[(r3.x & 0x1FFFF) * CH + lane];
        acc = fmaf(__int_as_float(r0.y), x0, acc);
        acc = fmaf(__int_as_float(r1.y), x1, acc);
        acc = fmaf(__int_as_float(r2.y), x2, acc);
        acc = fmaf(__int_as_float(r3.y), x3, acc);
      }
      for (; e < end; ++e) {
        const int2 rec = ebuf[e];
        acc = fmaf(__int_as_float(rec.y), xw[(rec.x & 0x1FFFF) * CH + lane], acc);
      }
    }
    out[row * CH + lane] = 1.f / (1.f + __expf(-acc));
  }
}

// ---------------------------------------------------------------------------
// Fallback path (ws too small): atomic scatter + sigmoid.
// ---------------------------------------------------------------------------
__global__ __launch_bounds__(256) void scatter_kernel(
    const int* __restrict__ rows, const int* __restrict__ cols,
    const float* __restrict__ vals, const float* __restrict__ xw,
    float* __restrict__ out, int nnz) {
  const int lane = threadIdx.x & 63;
  const int wid = (blockIdx.x * blockDim.x + threadIdx.x) >> 6;
  const int nwaves = (gridDim.x * blockDim.x) >> 6;
  for (int k = wid; k < nnz; k += nwaves) {
    const float xv = xw[cols[k] * CH + lane];
    atomicAdd(&out[rows[k] * CH + lane], vals[k] * xv);
  }
}

__global__ __launch_bounds__(256) void sigmoid_kernel(float* __restrict__ out, int n4) {
  const int i = blockIdx.x * blockDim.x + threadIdx.x;
  if (i < n4) {
    float4 v = reinterpret_cast<float4*>(out)[i];
    v.x = 1.f / (1.f + __expf(-v.x));
    v.y = 1.f / (1.f + __expf(-v.y));
    v.z = 1.f / (1.f + __expf(-v.z));
    v.w = 1.f / (1.f + __expf(-v.w));
    reinterpret_cast<float4*>(out)[i] = v;
  }
}

extern "C" void kernel_launch(void* const* d_in, const int* in_sizes, int n_in,
                              void* d_out, int out_size, void* d_ws, size_t ws_size,
                              hipStream_t stream) {
  const float* x         = (const float*)d_in[0];
  const int*   down_rows = (const int*)d_in[1];
  const int*   down_cols = (const int*)d_in[2];
  const float* down_vals = (const float*)d_in[3];
  const int*   up_rows   = (const int*)d_in[4];
  const int*   up_cols   = (const int*)d_in[5];
  const float* up_vals   = (const float*)d_in[6];
  const float* w_conv    = (const float*)d_in[7];
  const float* w_lin     = (const float*)d_in[8];

  const int n   = in_sizes[0] / CH;  // 100000
  const int nnz = in_sizes[1];       // 1600000
  const int tot = 2 * nnz;
  const int nb  = (n + RPB - 1) / RPB;  // 782

  float* out = (float*)d_out;

  // ws layout
  float* xw      = (float*)d_ws;                    // n*CH
  int*   soff    = (int*)(xw + (size_t)n * CH);     // nb*NBLK (counts -> scanned offsets)
  int*   partial = soff + (size_t)nb * NBLK;        // 1024
  int*   row_ptr = partial + 1024;                  // n+1
  int*   bflag   = row_ptr + n + 1;                 // nb
  int2*  ebuf    = (int2*)(bflag + nb);             // tot records (8B each)
  const size_t need =
      ((size_t)n * CH + (size_t)nb * NBLK + 1024 + (size_t)n + 1 + nb) * 4 +
      (size_t)tot * 8 + 16;

  // xw = x@w_conv (ws), out = x@w_lin (accumulator)
  gemm2_kernel<<<4096, 256, 0, stream>>>(x, w_conv, w_lin, xw, out, n);

  if (ws_size >= need && nb <= MAXNB && n < (1 << 17)) {
    const int ntot = nb * NBLK;
    const int nsb = (ntot + SCAN_B - 1) / SCAN_B;  // 783 <= 1024
    countT_kernel<<<NBLK, 256, 0, stream>>>(down_rows, up_rows, soff, nnz, nb);
    scan_partial<<<nsb, SCAN_B, 0, stream>>>(soff, partial, ntot);
    scan_partials_scan<<<1, 1024, 0, stream>>>(partial, nsb);
    scan_final<<<nsb, SCAN_B, 0, stream>>>(soff, partial, ntot);
    fillB_kernel<<<NBLK, 256, 0, stream>>>(down_rows, down_cols, down_vals,
                                           up_rows, up_cols, up_vals,
                                           soff, ebuf, nnz, nb);
    sortB_kernel<<<nb, 256, 0, stream>>>(soff, ebuf, row_ptr, bflag, n, nb, tot);
    const int nblk = (n + 3) / 4;  // 4 rows (waves) per 256-thread block
    gather_kernel<<<nblk, 256, 0, stream>>>(row_ptr, soff, bflag, ebuf, xw, out,
                                            n, nb, tot);
  } else {
    scatter_kernel<<<4096, 256, 0, stream>>>(down_rows, down_cols, down_vals, xw, out, nnz);
    scatter_kernel<<<4096, 256, 0, stream>>>(up_rows, up_cols, up_vals, xw, out, nnz);
    const int n4 = (n * CH) / 4;
    sigmoid_kernel<<<(n4 + 255) / 256, 256, 0, stream>>>(out, n4);
  }
}

// Round 5
// 206.779 us; speedup vs baseline: 7.2470x; 1.4708x over previous
//
#include <hip/hip_runtime.h>
#include <hip/hip_bf16.h>

#define CH 64
#define RPB 128      // rows per bucket
#define RPB_SH 7
#define NBLK 512     // count/fill blocks
#define MAXNB 800    // max buckets supported by LDS arrays
#define SCAN_B 512
#define CAP 6144     // max records per bucket for in-LDS sort

typedef __attribute__((ext_vector_type(8))) short short8;
typedef __attribute__((ext_vector_type(4))) float f32x4;

__device__ __forceinline__ unsigned short f2bf(float f) {
  unsigned int u = __float_as_uint(f);
  u = u + 0x7FFFu + ((u >> 16) & 1u);  // RNE
  return (unsigned short)(u >> 16);
}
__device__ __forceinline__ float bf2f(unsigned short s) {
  return __uint_as_float(((unsigned int)s) << 16);
}

// ---------------------------------------------------------------------------
// Kernel 1: fused dual GEMM via MFMA, split-bf16 (x=hi+lo, W=whi+wlo) for
// fp32-grade accuracy.  Waves 0-1: xw = x@w_conv -> bf16 ws.
//                       Waves 2-3: out = x@w_lin -> fp32 d_out.
// Per wave: 16 rows/iter; B-frags (both splits) held in registers.
// A layout: lane l elem j -> A[l&15][(l>>4)*8+j]; B: B[(l>>4)*8+j][l&15];
// C/D: col = l&15, row = (l>>4)*4 + reg  (m89-verified).
// ---------------------------------------------------------------------------
__global__ __launch_bounds__(256) void gemm_mfma_kernel(
    const float* __restrict__ x, const float* __restrict__ wc,
    const float* __restrict__ wl, unsigned short* __restrict__ xwb,
    float* __restrict__ out, int n) {
  const int lane = threadIdx.x & 63;
  const int wv = threadIdx.x >> 6;
  const int mat = wv >> 1;   // 0: conv, 1: lin
  const int tile = wv & 1;   // row-tile within 32-row group
  const float* __restrict__ W = mat ? wl : wc;

  const int i16 = lane & 15;
  const int kseg = lane >> 4;

  // Build B fragments (hi/lo splits) in registers: [nt][kk]
  short8 bhi[4][2], blo[4][2];
#pragma unroll
  for (int nt = 0; nt < 4; ++nt)
#pragma unroll
    for (int kk = 0; kk < 2; ++kk)
#pragma unroll
      for (int j = 0; j < 8; ++j) {
        const float w = W[(kk * 32 + kseg * 8 + j) * CH + nt * 16 + i16];
        const unsigned short h = f2bf(w);
        bhi[nt][kk][j] = (short)h;
        blo[nt][kk][j] = (short)f2bf(w - bf2f(h));
      }

  const int ngroups = (n + 31) >> 5;
  for (int g = blockIdx.x; g < ngroups; g += gridDim.x) {
    const int base = g * 32 + tile * 16;
    const int row = base + i16;
    const int rowc = (row < n) ? row : (n - 1);
    const float* xp = x + (size_t)rowc * CH + kseg * 8;

    float af[16];
    {
      const float4 p0 = *(const float4*)(xp);
      const float4 p1 = *(const float4*)(xp + 4);
      const float4 q0 = *(const float4*)(xp + 32);
      const float4 q1 = *(const float4*)(xp + 36);
      af[0] = p0.x; af[1] = p0.y; af[2] = p0.z; af[3] = p0.w;
      af[4] = p1.x; af[5] = p1.y; af[6] = p1.z; af[7] = p1.w;
      af[8] = q0.x; af[9] = q0.y; af[10] = q0.z; af[11] = q0.w;
      af[12] = q1.x; af[13] = q1.y; af[14] = q1.z; af[15] = q1.w;
    }
    short8 ahi[2], alo[2];
#pragma unroll
    for (int kk = 0; kk < 2; ++kk)
#pragma unroll
      for (int j = 0; j < 8; ++j) {
        const float f = af[kk * 8 + j];
        const unsigned short h = f2bf(f);
        ahi[kk][j] = (short)h;
        alo[kk][j] = (short)f2bf(f - bf2f(h));
      }

    f32x4 acc[4];
#pragma unroll
    for (int nt = 0; nt < 4; ++nt) {
      f32x4 a = {0.f, 0.f, 0.f, 0.f};
#pragma unroll
      for (int kk = 0; kk < 2; ++kk) {
        a = __builtin_amdgcn_mfma_f32_16x16x32_bf16(ahi[kk], bhi[nt][kk], a, 0, 0, 0);
        a = __builtin_amdgcn_mfma_f32_16x16x32_bf16(alo[kk], bhi[nt][kk], a, 0, 0, 0);
        a = __builtin_amdgcn_mfma_f32_16x16x32_bf16(ahi[kk], blo[nt][kk], a, 0, 0, 0);
      }
      acc[nt] = a;
    }

    if (mat == 0) {
#pragma unroll
      for (int nt = 0; nt < 4; ++nt)
#pragma unroll
        for (int r = 0; r < 4; ++r) {
          const int orow = base + kseg * 4 + r;
          if (orow < n)
            xwb[(size_t)orow * CH + nt * 16 + i16] = f2bf(acc[nt][r]);
        }
    } else {
#pragma unroll
      for (int nt = 0; nt < 4; ++nt)
#pragma unroll
        for (int r = 0; r < 4; ++r) {
          const int orow = base + kseg * 4 + r;
          if (orow < n)
            out[(size_t)orow * CH + nt * 16 + i16] = acc[nt][r];
        }
    }
  }
}

// ---------------------------------------------------------------------------
// Phase A: per-(bucket, block) edge counts via LDS histogram.
// ---------------------------------------------------------------------------
__global__ __launch_bounds__(256) void countT_kernel(
    const int* __restrict__ r1, const int* __restrict__ r2,
    int* __restrict__ countsT, int nnz, int nb) {
  __shared__ int h[MAXNB];
  for (int i = threadIdx.x; i < nb; i += 256) h[i] = 0;
  __syncthreads();
  const int tot = 2 * nnz;
  const int chunk = (tot + NBLK - 1) / NBLK;
  const int e0 = blockIdx.x * chunk;
  const int e1 = min(tot, e0 + chunk);
  for (int e = e0 + threadIdx.x; e < e1; e += 256) {
    const int r = (e < nnz) ? r1[e] : r2[e - nnz];
    atomicAdd(&h[r >> RPB_SH], 1);
  }
  __syncthreads();
  for (int b = threadIdx.x; b < nb; b += 256)
    countsT[b * NBLK + blockIdx.x] = h[b];
}

// ---------------------------------------------------------------------------
// Phase B: exclusive scan of countsT (length nb*NBLK), in place, 3 kernels.
// ---------------------------------------------------------------------------
__global__ __launch_bounds__(SCAN_B) void scan_partial(
    const int* __restrict__ in, int* __restrict__ partials, int n) {
  __shared__ int s[SCAN_B];
  const int i = blockIdx.x * SCAN_B + threadIdx.x;
  s[threadIdx.x] = (i < n) ? in[i] : 0;
  __syncthreads();
  for (int off = SCAN_B / 2; off > 0; off >>= 1) {
    if (threadIdx.x < off) s[threadIdx.x] += s[threadIdx.x + off];
    __syncthreads();
  }
  if (threadIdx.x == 0) partials[blockIdx.x] = s[0];
}

__global__ __launch_bounds__(1024) void scan_partials_scan(
    int* __restrict__ partials, int nb) {
  __shared__ int s[1024];
  const int v = (threadIdx.x < nb) ? partials[threadIdx.x] : 0;
  s[threadIdx.x] = v;
  __syncthreads();
  for (int off = 1; off < 1024; off <<= 1) {
    const int t = (threadIdx.x >= off) ? s[threadIdx.x - off] : 0;
    __syncthreads();
    s[threadIdx.x] += t;
    __syncthreads();
  }
  if (threadIdx.x < nb) partials[threadIdx.x] = s[threadIdx.x] - v;  // exclusive
}

__global__ __launch_bounds__(SCAN_B) void scan_final(
    int* __restrict__ data, const int* __restrict__ partials, int n) {
  __shared__ int s[SCAN_B];
  const int i = blockIdx.x * SCAN_B + threadIdx.x;
  const int v = (i < n) ? data[i] : 0;
  s[threadIdx.x] = v;
  __syncthreads();
  for (int off = 1; off < SCAN_B; off <<= 1) {
    const int t = (threadIdx.x >= off) ? s[threadIdx.x - off] : 0;
    __syncthreads();
    s[threadIdx.x] += t;
    __syncthreads();
  }
  if (i < n) data[i] = s[threadIdx.x] - v + partials[blockIdx.x];  // exclusive
}

// ---------------------------------------------------------------------------
// Phase C: fill bucketed edge records. LDS cursors only.
// record.x = ((row & 127) << 17) | col,  record.y = val bits
// ---------------------------------------------------------------------------
__global__ __launch_bounds__(256) void fillB_kernel(
    const int* __restrict__ r1, const int* __restrict__ c1, const float* __restrict__ v1,
    const int* __restrict__ r2, const int* __restrict__ c2, const float* __restrict__ v2,
    const int* __restrict__ soff, int2* __restrict__ ebuf, int nnz, int nb) {
  __shared__ int cur[MAXNB];
  for (int b = threadIdx.x; b < nb; b += 256)
    cur[b] = soff[b * NBLK + blockIdx.x];
  __syncthreads();
  const int tot = 2 * nnz;
  const int chunk = (tot + NBLK - 1) / NBLK;
  const int e0 = blockIdx.x * chunk;
  const int e1 = min(tot, e0 + chunk);
  for (int e = e0 + threadIdx.x; e < e1; e += 256) {
    int r, c;
    float v;
    if (e < nnz) {
      r = r1[e]; c = c1[e]; v = v1[e];
    } else {
      r = r2[e - nnz]; c = c2[e - nnz]; v = v2[e - nnz];
    }
    const int b = r >> RPB_SH;
    const int slot = atomicAdd(&cur[b], 1);
    ebuf[slot] = make_int2(((r & (RPB - 1)) << 17) | c, __float_as_int(v));
  }
}

// ---------------------------------------------------------------------------
// Phase D: in-bucket counting sort (one block per bucket). Emits row_ptr.
// ---------------------------------------------------------------------------
__global__ __launch_bounds__(256) void sortB_kernel(
    const int* __restrict__ soff, int2* __restrict__ ebuf,
    int* __restrict__ row_ptr, int* __restrict__ bflag,
    int n, int nb, int tot) {
  __shared__ int2 raw[CAP];   // 48 KB
  __shared__ int hist[RPB];
  __shared__ int sc[RPB];
  __shared__ int cur[RPB];
  const int b = blockIdx.x;
  const int beg = soff[b * NBLK];
  const int end = (b + 1 < nb) ? soff[(b + 1) * NBLK] : tot;
  const int cnt = end - beg;

  if (b == nb - 1 && threadIdx.x == 0) row_ptr[n] = tot;

  if (cnt > CAP) {
    if (threadIdx.x == 0) bflag[b] = 1;
    const int r0 = b * RPB;
    for (int r = threadIdx.x; r < RPB; r += 256) {
      const int gr = r0 + r;
      if (gr < n) row_ptr[gr] = beg;
    }
    return;
  }
  if (threadIdx.x == 0) bflag[b] = 0;
  if (threadIdx.x < RPB) hist[threadIdx.x] = 0;
  __syncthreads();

  for (int i = threadIdx.x; i < cnt; i += 256) {
    const int2 rec = ebuf[beg + i];
    raw[i] = rec;
    atomicAdd(&hist[rec.x >> 17], 1);
  }
  __syncthreads();

  int v = 0;
  if (threadIdx.x < RPB) {
    v = hist[threadIdx.x];
    sc[threadIdx.x] = v;
  }
  __syncthreads();
  for (int off = 1; off < RPB; off <<= 1) {
    int t = 0;
    if (threadIdx.x < RPB && threadIdx.x >= off) t = sc[threadIdx.x - off];
    __syncthreads();
    if (threadIdx.x < RPB) sc[threadIdx.x] += t;
    __syncthreads();
  }
  if (threadIdx.x < RPB) {
    const int ex = sc[threadIdx.x] - v;
    cur[threadIdx.x] = ex;
    const int gr = b * RPB + threadIdx.x;
    if (gr < n) row_ptr[gr] = beg + ex;
  }
  __syncthreads();

  for (int i = threadIdx.x; i < cnt; i += 256) {
    const int2 rec = raw[i];
    const int pos = atomicAdd(&cur[rec.x >> 17], 1);
    ebuf[beg + pos] = rec;
  }
}

// ---------------------------------------------------------------------------
// Phase E: row gather — one wave per row, bf16 xw reads, fused sigmoid.
// ---------------------------------------------------------------------------
__global__ __launch_bounds__(256) void gather_kernel(
    const int* __restrict__ row_ptr, const int* __restrict__ soff,
    const int* __restrict__ bflag, const int2* __restrict__ ebuf,
    const unsigned short* __restrict__ xwb, float* __restrict__ out,
    int n, int nb, int tot) {
  const int lane = threadIdx.x & 63;
  const int w = (blockIdx.x * blockDim.x + threadIdx.x) >> 6;
  const int nw = (gridDim.x * blockDim.x) >> 6;
  for (int row = w; row < n; row += nw) {
    float acc = out[(size_t)row * CH + lane];  // linear term
    const int b = row >> RPB_SH;
    if (bflag[b]) {  // unsorted bucket fallback: predicated scan
      const int bb = soff[b * NBLK];
      const int be = (b + 1 < nb) ? soff[(b + 1) * NBLK] : tot;
      const int rl = row & (RPB - 1);
      for (int e = bb; e < be; ++e) {
        const int2 rec = ebuf[e];
        if ((rec.x >> 17) == rl)
          acc = fmaf(__int_as_float(rec.y),
                     bf2f(xwb[(size_t)(rec.x & 0x1FFFF) * CH + lane]), acc);
      }
    } else {
      const int beg = row_ptr[row];
      const int end = row_ptr[row + 1];
      int e = beg;
      for (; e + 8 <= end; e += 8) {
        float xv[8], vv[8];
#pragma unroll
        for (int j = 0; j < 8; ++j) {
          const int2 rc = ebuf[e + j];
          vv[j] = __int_as_float(rc.y);
          xv[j] = bf2f(xwb[(size_t)(rc.x & 0x1FFFF) * CH + lane]);
        }
#pragma unroll
        for (int j = 0; j < 8; ++j) acc = fmaf(vv[j], xv[j], acc);
      }
      for (; e < end; ++e) {
        const int2 rec = ebuf[e];
        acc = fmaf(__int_as_float(rec.y),
                   bf2f(xwb[(size_t)(rec.x & 0x1FFFF) * CH + lane]), acc);
      }
    }
    out[(size_t)row * CH + lane] = 1.f / (1.f + __expf(-acc));
  }
}

// ---------------------------------------------------------------------------
// Fallback path (ws too small): atomic scatter + sigmoid.
// ---------------------------------------------------------------------------
__global__ __launch_bounds__(256) void scatter_kernel(
    const int* __restrict__ rows, const int* __restrict__ cols,
    const float* __restrict__ vals, const unsigned short* __restrict__ xwb,
    float* __restrict__ out, int nnz) {
  const int lane = threadIdx.x & 63;
  const int wid = (blockIdx.x * blockDim.x + threadIdx.x) >> 6;
  const int nwaves = (gridDim.x * blockDim.x) >> 6;
  for (int k = wid; k < nnz; k += nwaves) {
    const float xv = bf2f(xwb[(size_t)cols[k] * CH + lane]);
    atomicAdd(&out[(size_t)rows[k] * CH + lane], vals[k] * xv);
  }
}

__global__ __launch_bounds__(256) void sigmoid_kernel(float* __restrict__ out, int n4) {
  const int i = blockIdx.x * blockDim.x + threadIdx.x;
  if (i < n4) {
    float4 v = reinterpret_cast<float4*>(out)[i];
    v.x = 1.f / (1.f + __expf(-v.x));
    v.y = 1.f / (1.f + __expf(-v.y));
    v.z = 1.f / (1.f + __expf(-v.z));
    v.w = 1.f / (1.f + __expf(-v.w));
    reinterpret_cast<float4*>(out)[i] = v;
  }
}

extern "C" void kernel_launch(void* const* d_in, const int* in_sizes, int n_in,
                              void* d_out, int out_size, void* d_ws, size_t ws_size,
                              hipStream_t stream) {
  const float* x         = (const float*)d_in[0];
  const int*   down_rows = (const int*)d_in[1];
  const int*   down_cols = (const int*)d_in[2];
  const float* down_vals = (const float*)d_in[3];
  const int*   up_rows   = (const int*)d_in[4];
  const int*   up_cols   = (const int*)d_in[5];
  const float* up_vals   = (const float*)d_in[6];
  const float* w_conv    = (const float*)d_in[7];
  const float* w_lin     = (const float*)d_in[8];

  const int n   = in_sizes[0] / CH;  // 100000
  const int nnz = in_sizes[1];       // 1600000
  const int tot = 2 * nnz;
  const int nb  = (n + RPB - 1) / RPB;  // 782

  float* out = (float*)d_out;

  // ws layout (xw stored as bf16)
  char* p = (char*)d_ws;
  unsigned short* xwb = (unsigned short*)p;  p += (size_t)n * CH * 2;
  int* soff    = (int*)p;  p += (size_t)nb * NBLK * 4;
  int* partial = (int*)p;  p += 1024 * 4;
  int* row_ptr = (int*)p;  p += ((size_t)n + 2) * 4;
  int* bflag   = (int*)p;  p += (size_t)nb * 4;
  p = (char*)(((uintptr_t)p + 7) & ~(uintptr_t)7);
  int2* ebuf   = (int2*)p; p += (size_t)tot * 8;
  const size_t need = (size_t)(p - (char*)d_ws);

  // xw = bf16(x@w_conv) (ws), out = x@w_lin (fp32 accumulator)
  gemm_mfma_kernel<<<1024, 256, 0, stream>>>(x, w_conv, w_lin, xwb, out, n);

  if (ws_size >= need && nb <= MAXNB && n < (1 << 17)) {
    const int ntot = nb * NBLK;
    const int nsb = (ntot + SCAN_B - 1) / SCAN_B;  // 783 <= 1024
    countT_kernel<<<NBLK, 256, 0, stream>>>(down_rows, up_rows, soff, nnz, nb);
    scan_partial<<<nsb, SCAN_B, 0, stream>>>(soff, partial, ntot);
    scan_partials_scan<<<1, 1024, 0, stream>>>(partial, nsb);
    scan_final<<<nsb, SCAN_B, 0, stream>>>(soff, partial, ntot);
    fillB_kernel<<<NBLK, 256, 0, stream>>>(down_rows, down_cols, down_vals,
                                           up_rows, up_cols, up_vals,
                                           soff, ebuf, nnz, nb);
    sortB_kernel<<<nb, 256, 0, stream>>>(soff, ebuf, row_ptr, bflag, n, nb, tot);
    const int nblk = (n + 3) / 4;
    gather_kernel<<<nblk, 256, 0, stream>>>(row_ptr, soff, bflag, ebuf, xwb, out,
                                            n, nb, tot);
  } else {
    scatter_kernel<<<4096, 256, 0, stream>>>(down_rows, down_cols, down_vals, xwb, out, nnz);
    scatter_kernel<<<4096, 256, 0, stream>>>(up_rows, up_cols, up_vals, xwb, out, nnz);
    const int n4 = (n * CH) / 4;
    sigmoid_kernel<<<(n4 + 255) / 256, 256, 0, stream>>>(out, n4);
  }
}

// Round 6
// 195.111 us; speedup vs baseline: 7.6804x; 1.0598x over previous
//
#include <hip/hip_runtime.h>
#include <hip/hip_bf16.h>

#define CH 64
#define RPB 128      // rows per bucket
#define RPB_SH 7
#define NBLK 256     // count/fill blocks
#define MAXNB 800    // max buckets supported by LDS arrays
#define SCAN_B 512
#define CAP 6144     // max records per bucket for in-LDS sort

typedef __attribute__((ext_vector_type(8))) short short8;
typedef __attribute__((ext_vector_type(4))) float f32x4;

__device__ __forceinline__ unsigned short f2bf(float f) {
  unsigned int u = __float_as_uint(f);
  u = u + 0x7FFFu + ((u >> 16) & 1u);  // RNE
  return (unsigned short)(u >> 16);
}
__device__ __forceinline__ float bf2f(unsigned short s) {
  return __uint_as_float(((unsigned int)s) << 16);
}

// ---------------------------------------------------------------------------
// Kernel 1: fused dual GEMM via MFMA, split-bf16 for fp32-grade accuracy.
// Waves 0-1: xw = x@w_conv -> bf16 ws.  Waves 2-3: out = x@w_lin -> fp32.
// ---------------------------------------------------------------------------
__global__ __launch_bounds__(256) void gemm_mfma_kernel(
    const float* __restrict__ x, const float* __restrict__ wc,
    const float* __restrict__ wl, unsigned short* __restrict__ xwb,
    float* __restrict__ out, int n) {
  const int lane = threadIdx.x & 63;
  const int wv = threadIdx.x >> 6;
  const int mat = wv >> 1;   // 0: conv, 1: lin
  const int tile = wv & 1;   // row-tile within 32-row group
  const float* __restrict__ W = mat ? wl : wc;

  const int i16 = lane & 15;
  const int kseg = lane >> 4;

  short8 bhi[4][2], blo[4][2];
#pragma unroll
  for (int nt = 0; nt < 4; ++nt)
#pragma unroll
    for (int kk = 0; kk < 2; ++kk)
#pragma unroll
      for (int j = 0; j < 8; ++j) {
        const float w = W[(kk * 32 + kseg * 8 + j) * CH + nt * 16 + i16];
        const unsigned short h = f2bf(w);
        bhi[nt][kk][j] = (short)h;
        blo[nt][kk][j] = (short)f2bf(w - bf2f(h));
      }

  const int ngroups = (n + 31) >> 5;
  for (int g = blockIdx.x; g < ngroups; g += gridDim.x) {
    const int base = g * 32 + tile * 16;
    const int row = base + i16;
    const int rowc = (row < n) ? row : (n - 1);
    const float* xp = x + (size_t)rowc * CH + kseg * 8;

    float af[16];
    {
      const float4 p0 = *(const float4*)(xp);
      const float4 p1 = *(const float4*)(xp + 4);
      const float4 q0 = *(const float4*)(xp + 32);
      const float4 q1 = *(const float4*)(xp + 36);
      af[0] = p0.x; af[1] = p0.y; af[2] = p0.z; af[3] = p0.w;
      af[4] = p1.x; af[5] = p1.y; af[6] = p1.z; af[7] = p1.w;
      af[8] = q0.x; af[9] = q0.y; af[10] = q0.z; af[11] = q0.w;
      af[12] = q1.x; af[13] = q1.y; af[14] = q1.z; af[15] = q1.w;
    }
    short8 ahi[2], alo[2];
#pragma unroll
    for (int kk = 0; kk < 2; ++kk)
#pragma unroll
      for (int j = 0; j < 8; ++j) {
        const float f = af[kk * 8 + j];
        const unsigned short h = f2bf(f);
        ahi[kk][j] = (short)h;
        alo[kk][j] = (short)f2bf(f - bf2f(h));
      }

    f32x4 acc[4];
#pragma unroll
    for (int nt = 0; nt < 4; ++nt) {
      f32x4 a = {0.f, 0.f, 0.f, 0.f};
#pragma unroll
      for (int kk = 0; kk < 2; ++kk) {
        a = __builtin_amdgcn_mfma_f32_16x16x32_bf16(ahi[kk], bhi[nt][kk], a, 0, 0, 0);
        a = __builtin_amdgcn_mfma_f32_16x16x32_bf16(alo[kk], bhi[nt][kk], a, 0, 0, 0);
        a = __builtin_amdgcn_mfma_f32_16x16x32_bf16(ahi[kk], blo[nt][kk], a, 0, 0, 0);
      }
      acc[nt] = a;
    }

    if (mat == 0) {
#pragma unroll
      for (int nt = 0; nt < 4; ++nt)
#pragma unroll
        for (int r = 0; r < 4; ++r) {
          const int orow = base + kseg * 4 + r;
          if (orow < n)
            xwb[(size_t)orow * CH + nt * 16 + i16] = f2bf(acc[nt][r]);
        }
    } else {
#pragma unroll
      for (int nt = 0; nt < 4; ++nt)
#pragma unroll
        for (int r = 0; r < 4; ++r) {
          const int orow = base + kseg * 4 + r;
          if (orow < n)
            out[(size_t)orow * CH + nt * 16 + i16] = acc[nt][r];
        }
    }
  }
}

// ---------------------------------------------------------------------------
// Phase A: per-(bucket, block) edge counts via LDS histogram.
// ---------------------------------------------------------------------------
__global__ __launch_bounds__(256) void countT_kernel(
    const int* __restrict__ r1, const int* __restrict__ r2,
    int* __restrict__ countsT, int nnz, int nb) {
  __shared__ int h[MAXNB];
  for (int i = threadIdx.x; i < nb; i += 256) h[i] = 0;
  __syncthreads();
  const int tot = 2 * nnz;
  const int chunk = (tot + NBLK - 1) / NBLK;
  const int e0 = blockIdx.x * chunk;
  const int e1 = min(tot, e0 + chunk);
  for (int e = e0 + threadIdx.x; e < e1; e += 256) {
    const int r = (e < nnz) ? r1[e] : r2[e - nnz];
    atomicAdd(&h[r >> RPB_SH], 1);
  }
  __syncthreads();
  for (int b = threadIdx.x; b < nb; b += 256)
    countsT[b * NBLK + blockIdx.x] = h[b];
}

// ---------------------------------------------------------------------------
// Phase B: exclusive scan of countsT (length nb*NBLK), in place, 3 kernels.
// ---------------------------------------------------------------------------
__global__ __launch_bounds__(SCAN_B) void scan_partial(
    const int* __restrict__ in, int* __restrict__ partials, int n) {
  __shared__ int s[SCAN_B];
  const int i = blockIdx.x * SCAN_B + threadIdx.x;
  s[threadIdx.x] = (i < n) ? in[i] : 0;
  __syncthreads();
  for (int off = SCAN_B / 2; off > 0; off >>= 1) {
    if (threadIdx.x < off) s[threadIdx.x] += s[threadIdx.x + off];
    __syncthreads();
  }
  if (threadIdx.x == 0) partials[blockIdx.x] = s[0];
}

__global__ __launch_bounds__(1024) void scan_partials_scan(
    int* __restrict__ partials, int nb) {
  __shared__ int s[1024];
  const int v = (threadIdx.x < nb) ? partials[threadIdx.x] : 0;
  s[threadIdx.x] = v;
  __syncthreads();
  for (int off = 1; off < 1024; off <<= 1) {
    const int t = (threadIdx.x >= off) ? s[threadIdx.x - off] : 0;
    __syncthreads();
    s[threadIdx.x] += t;
    __syncthreads();
  }
  if (threadIdx.x < nb) partials[threadIdx.x] = s[threadIdx.x] - v;  // exclusive
}

__global__ __launch_bounds__(SCAN_B) void scan_final(
    int* __restrict__ data, const int* __restrict__ partials, int n) {
  __shared__ int s[SCAN_B];
  const int i = blockIdx.x * SCAN_B + threadIdx.x;
  const int v = (i < n) ? data[i] : 0;
  s[threadIdx.x] = v;
  __syncthreads();
  for (int off = 1; off < SCAN_B; off <<= 1) {
    const int t = (threadIdx.x >= off) ? s[threadIdx.x - off] : 0;
    __syncthreads();
    s[threadIdx.x] += t;
    __syncthreads();
  }
  if (i < n) data[i] = s[threadIdx.x] - v + partials[blockIdx.x];  // exclusive
}

// ---------------------------------------------------------------------------
// Phase C: fill bucketed edge records. LDS cursors only.
// record.x = ((row & 127) << 17) | col,  record.y = val bits
// ---------------------------------------------------------------------------
__global__ __launch_bounds__(256) void fillB_kernel(
    const int* __restrict__ r1, const int* __restrict__ c1, const float* __restrict__ v1,
    const int* __restrict__ r2, const int* __restrict__ c2, const float* __restrict__ v2,
    const int* __restrict__ soff, int2* __restrict__ ebuf, int nnz, int nb) {
  __shared__ int cur[MAXNB];
  for (int b = threadIdx.x; b < nb; b += 256)
    cur[b] = soff[b * NBLK + blockIdx.x];
  __syncthreads();
  const int tot = 2 * nnz;
  const int chunk = (tot + NBLK - 1) / NBLK;
  const int e0 = blockIdx.x * chunk;
  const int e1 = min(tot, e0 + chunk);
  for (int e = e0 + threadIdx.x; e < e1; e += 256) {
    int r, c;
    float v;
    if (e < nnz) {
      r = r1[e]; c = c1[e]; v = v1[e];
    } else {
      r = r2[e - nnz]; c = c2[e - nnz]; v = v2[e - nnz];
    }
    const int b = r >> RPB_SH;
    const int slot = atomicAdd(&cur[b], 1);
    ebuf[slot] = make_int2(((r & (RPB - 1)) << 17) | c, __float_as_int(v));
  }
}

// ---------------------------------------------------------------------------
// Phase D: in-bucket counting sort (one block per bucket). Emits row_ptr.
// ---------------------------------------------------------------------------
__global__ __launch_bounds__(256) void sortB_kernel(
    const int* __restrict__ soff, int2* __restrict__ ebuf,
    int* __restrict__ row_ptr, int* __restrict__ bflag,
    int n, int nb, int tot) {
  __shared__ int2 raw[CAP];   // 48 KB
  __shared__ int hist[RPB];
  __shared__ int sc[RPB];
  __shared__ int cur[RPB];
  const int b = blockIdx.x;
  const int beg = soff[b * NBLK];
  const int end = (b + 1 < nb) ? soff[(b + 1) * NBLK] : tot;
  const int cnt = end - beg;

  if (b == nb - 1 && threadIdx.x == 0) row_ptr[n] = tot;

  if (cnt > CAP) {
    if (threadIdx.x == 0) bflag[b] = 1;
    const int r0 = b * RPB;
    for (int r = threadIdx.x; r < RPB; r += 256) {
      const int gr = r0 + r;
      if (gr < n) row_ptr[gr] = beg;
    }
    return;
  }
  if (threadIdx.x == 0) bflag[b] = 0;
  if (threadIdx.x < RPB) hist[threadIdx.x] = 0;
  __syncthreads();

  for (int i = threadIdx.x; i < cnt; i += 256) {
    const int2 rec = ebuf[beg + i];
    raw[i] = rec;
    atomicAdd(&hist[rec.x >> 17], 1);
  }
  __syncthreads();

  int v = 0;
  if (threadIdx.x < RPB) {
    v = hist[threadIdx.x];
    sc[threadIdx.x] = v;
  }
  __syncthreads();
  for (int off = 1; off < RPB; off <<= 1) {
    int t = 0;
    if (threadIdx.x < RPB && threadIdx.x >= off) t = sc[threadIdx.x - off];
    __syncthreads();
    if (threadIdx.x < RPB) sc[threadIdx.x] += t;
    __syncthreads();
  }
  if (threadIdx.x < RPB) {
    const int ex = sc[threadIdx.x] - v;
    cur[threadIdx.x] = ex;
    const int gr = b * RPB + threadIdx.x;
    if (gr < n) row_ptr[gr] = beg + ex;
  }
  __syncthreads();

  for (int i = threadIdx.x; i < cnt; i += 256) {
    const int2 rec = raw[i];
    const int pos = atomicAdd(&cur[rec.x >> 17], 1);
    ebuf[beg + pos] = rec;
  }
}

// ---------------------------------------------------------------------------
// Phase E: row gather — half-wave dual-edge scheme. Lane owns a channel PAIR
// (one uint = 2 bf16); lanes 0-31 process even edges, 32-63 odd edges.
// 8 dword-gathers in flight cover 16 edges. shfl_xor(32) merges halves.
// ---------------------------------------------------------------------------
__global__ __launch_bounds__(256) void gather_kernel(
    const int* __restrict__ row_ptr, const int* __restrict__ soff,
    const int* __restrict__ bflag, const int2* __restrict__ ebuf,
    const unsigned int* __restrict__ xw32, float2* __restrict__ out2,
    int n, int nb, int tot) {
  const int lane = threadIdx.x & 63;
  const int half = lane >> 5;
  const int l32 = lane & 31;
  const int w = (blockIdx.x * blockDim.x + threadIdx.x) >> 6;
  const int nw = (gridDim.x * blockDim.x) >> 6;

  for (int row = w; row < n; row += nw) {
    float2 acc;
    if (half == 0) acc = out2[(size_t)row * 32 + l32];  // linear term
    else acc = make_float2(0.f, 0.f);

    const int b = row >> RPB_SH;
    if (bflag[b]) {  // degenerate fallback (never hit for random data)
      const int bb = soff[b * NBLK];
      const int be = (b + 1 < nb) ? soff[(b + 1) * NBLK] : tot;
      const int rl = row & (RPB - 1);
      for (int e = bb; e < be; ++e) {
        const int2 rec = ebuf[e];
        if ((rec.x >> 17) == rl && half == 0) {
          const unsigned int u = xw32[(size_t)(rec.x & 0x1FFFF) * 32 + l32];
          const float v = __int_as_float(rec.y);
          acc.x = fmaf(v, __uint_as_float(u << 16), acc.x);
          acc.y = fmaf(v, __uint_as_float(u & 0xFFFF0000u), acc.y);
        }
      }
    } else {
      const int beg = row_ptr[row];
      const int end = row_ptr[row + 1];
      int e = beg;
      for (; e + 16 <= end; e += 16) {
        int2 rc[8];
        unsigned int u[8];
#pragma unroll
        for (int j = 0; j < 8; ++j) rc[j] = ebuf[e + 2 * j + half];
#pragma unroll
        for (int j = 0; j < 8; ++j)
          u[j] = xw32[(size_t)(rc[j].x & 0x1FFFF) * 32 + l32];
#pragma unroll
        for (int j = 0; j < 8; ++j) {
          const float v = __int_as_float(rc[j].y);
          acc.x = fmaf(v, __uint_as_float(u[j] << 16), acc.x);
          acc.y = fmaf(v, __uint_as_float(u[j] & 0xFFFF0000u), acc.y);
        }
      }
      for (; e < end; e += 2) {
        const int idx = e + half;
        const bool ok = idx < end;
        const int2 rc = ebuf[ok ? idx : (end - 1)];
        const unsigned int u = xw32[(size_t)(rc.x & 0x1FFFF) * 32 + l32];
        const float v = ok ? __int_as_float(rc.y) : 0.f;
        acc.x = fmaf(v, __uint_as_float(u << 16), acc.x);
        acc.y = fmaf(v, __uint_as_float(u & 0xFFFF0000u), acc.y);
      }
    }

    // merge halves, fused sigmoid, write (lanes 0-31)
    acc.x += __shfl_xor(acc.x, 32, 64);
    acc.y += __shfl_xor(acc.y, 32, 64);
    if (half == 0) {
      acc.x = 1.f / (1.f + __expf(-acc.x));
      acc.y = 1.f / (1.f + __expf(-acc.y));
      out2[(size_t)row * 32 + l32] = acc;
    }
  }
}

// ---------------------------------------------------------------------------
// Fallback path (ws too small): atomic scatter + sigmoid.
// ---------------------------------------------------------------------------
__global__ __launch_bounds__(256) void scatter_kernel(
    const int* __restrict__ rows, const int* __restrict__ cols,
    const float* __restrict__ vals, const unsigned short* __restrict__ xwb,
    float* __restrict__ out, int nnz) {
  const int lane = threadIdx.x & 63;
  const int wid = (blockIdx.x * blockDim.x + threadIdx.x) >> 6;
  const int nwaves = (gridDim.x * blockDim.x) >> 6;
  for (int k = wid; k < nnz; k += nwaves) {
    const float xv = bf2f(xwb[(size_t)cols[k] * CH + lane]);
    atomicAdd(&out[(size_t)rows[k] * CH + lane], vals[k] * xv);
  }
}

__global__ __launch_bounds__(256) void sigmoid_kernel(float* __restrict__ out, int n4) {
  const int i = blockIdx.x * blockDim.x + threadIdx.x;
  if (i < n4) {
    float4 v = reinterpret_cast<float4*>(out)[i];
    v.x = 1.f / (1.f + __expf(-v.x));
    v.y = 1.f / (1.f + __expf(-v.y));
    v.z = 1.f / (1.f + __expf(-v.z));
    v.w = 1.f / (1.f + __expf(-v.w));
    reinterpret_cast<float4*>(out)[i] = v;
  }
}

extern "C" void kernel_launch(void* const* d_in, const int* in_sizes, int n_in,
                              void* d_out, int out_size, void* d_ws, size_t ws_size,
                              hipStream_t stream) {
  const float* x         = (const float*)d_in[0];
  const int*   down_rows = (const int*)d_in[1];
  const int*   down_cols = (const int*)d_in[2];
  const float* down_vals = (const float*)d_in[3];
  const int*   up_rows   = (const int*)d_in[4];
  const int*   up_cols   = (const int*)d_in[5];
  const float* up_vals   = (const float*)d_in[6];
  const float* w_conv    = (const float*)d_in[7];
  const float* w_lin     = (const float*)d_in[8];

  const int n   = in_sizes[0] / CH;  // 100000
  const int nnz = in_sizes[1];       // 1600000
  const int tot = 2 * nnz;
  const int nb  = (n + RPB - 1) / RPB;  // 782

  float* out = (float*)d_out;

  // ws layout (xw stored as bf16)
  char* p = (char*)d_ws;
  unsigned short* xwb = (unsigned short*)p;  p += (size_t)n * CH * 2;
  int* soff    = (int*)p;  p += (size_t)nb * NBLK * 4;
  int* partial = (int*)p;  p += 1024 * 4;
  int* row_ptr = (int*)p;  p += ((size_t)n + 2) * 4;
  int* bflag   = (int*)p;  p += (size_t)nb * 4;
  p = (char*)(((uintptr_t)p + 7) & ~(uintptr_t)7);
  int2* ebuf   = (int2*)p; p += (size_t)tot * 8;
  const size_t need = (size_t)(p - (char*)d_ws);

  // xw = bf16(x@w_conv) (ws), out = x@w_lin (fp32 accumulator)
  gemm_mfma_kernel<<<1024, 256, 0, stream>>>(x, w_conv, w_lin, xwb, out, n);

  if (ws_size >= need && nb <= MAXNB && n < (1 << 17)) {
    const int ntot = nb * NBLK;
    const int nsb = (ntot + SCAN_B - 1) / SCAN_B;  // 391 <= 1024
    countT_kernel<<<NBLK, 256, 0, stream>>>(down_rows, up_rows, soff, nnz, nb);
    scan_partial<<<nsb, SCAN_B, 0, stream>>>(soff, partial, ntot);
    scan_partials_scan<<<1, 1024, 0, stream>>>(partial, nsb);
    scan_final<<<nsb, SCAN_B, 0, stream>>>(soff, partial, ntot);
    fillB_kernel<<<NBLK, 256, 0, stream>>>(down_rows, down_cols, down_vals,
                                           up_rows, up_cols, up_vals,
                                           soff, ebuf, nnz, nb);
    sortB_kernel<<<nb, 256, 0, stream>>>(soff, ebuf, row_ptr, bflag, n, nb, tot);
    const int nblk = (n + 3) / 4;
    gather_kernel<<<nblk, 256, 0, stream>>>(row_ptr, soff, bflag, ebuf,
                                            (const unsigned int*)xwb,
                                            (float2*)out, n, nb, tot);
  } else {
    scatter_kernel<<<4096, 256, 0, stream>>>(down_rows, down_cols, down_vals, xwb, out, nnz);
    scatter_kernel<<<4096, 256, 0, stream>>>(up_rows, up_cols, up_vals, xwb, out, nnz);
    const int n4 = (n * CH) / 4;
    sigmoid_kernel<<<(n4 + 255) / 256, 256, 0, stream>>>(out, n4);
  }
}

// Round 7
// 181.344 us; speedup vs baseline: 8.2635x; 1.0759x over previous
//
#include <hip/hip_runtime.h>
#include <hip/hip_bf16.h>

#define CH 64
#define RPB 128      // rows per bucket
#define RPB_SH 7
#define NBLK 256     // count/fill chunk count
#define MAXNB 800    // max buckets supported by LDS arrays
#define SCAN_B 512
#define CAP 4608     // max records per bucket for in-LDS sort (mean 4096 + 8 sigma)
#define GEMM_BLOCKS 1024

typedef __attribute__((ext_vector_type(8))) short short8;
typedef __attribute__((ext_vector_type(4))) float f32x4;

__device__ __forceinline__ unsigned short f2bf(float f) {
  unsigned int u = __float_as_uint(f);
  u = u + 0x7FFFu + ((u >> 16) & 1u);  // RNE
  return (unsigned short)(u >> 16);
}
__device__ __forceinline__ float bf2f(unsigned short s) {
  return __uint_as_float(((unsigned int)s) << 16);
}

// ---------------------------------------------------------------------------
// Kernel 1 (merged): blocks [0, GEMM_BLOCKS) run the fused dual GEMM (MFMA,
// split-bf16). Blocks [GEMM_BLOCKS, GEMM_BLOCKS+NBLK) run countT (per-bucket
// LDS histogram). Independent work — countT hides under the GEMM.
// ---------------------------------------------------------------------------
__global__ __launch_bounds__(256) void gemm_count_kernel(
    const float* __restrict__ x, const float* __restrict__ wc,
    const float* __restrict__ wl, unsigned short* __restrict__ xwb,
    float* __restrict__ out, int n,
    const int* __restrict__ r1, const int* __restrict__ r2,
    int* __restrict__ countsT, int nnz, int nb) {
  __shared__ int h[MAXNB];

  if (blockIdx.x >= GEMM_BLOCKS) {
    // ---- countT path ----
    const int blk = blockIdx.x - GEMM_BLOCKS;
    for (int i = threadIdx.x; i < nb; i += 256) h[i] = 0;
    __syncthreads();
    const int tot = 2 * nnz;
    const int chunk = (tot + NBLK - 1) / NBLK;
    const int e0 = blk * chunk;
    const int e1 = min(tot, e0 + chunk);
    for (int e = e0 + threadIdx.x; e < e1; e += 256) {
      const int r = (e < nnz) ? r1[e] : r2[e - nnz];
      atomicAdd(&h[r >> RPB_SH], 1);
    }
    __syncthreads();
    for (int b = threadIdx.x; b < nb; b += 256)
      countsT[b * NBLK + blk] = h[b];
    return;
  }

  // ---- GEMM path ----
  const int lane = threadIdx.x & 63;
  const int wv = threadIdx.x >> 6;
  const int mat = wv >> 1;   // 0: conv, 1: lin
  const int tile = wv & 1;   // row-tile within 32-row group
  const float* __restrict__ W = mat ? wl : wc;

  const int i16 = lane & 15;
  const int kseg = lane >> 4;

  short8 bhi[4][2], blo[4][2];
#pragma unroll
  for (int nt = 0; nt < 4; ++nt)
#pragma unroll
    for (int kk = 0; kk < 2; ++kk)
#pragma unroll
      for (int j = 0; j < 8; ++j) {
        const float w = W[(kk * 32 + kseg * 8 + j) * CH + nt * 16 + i16];
        const unsigned short hh = f2bf(w);
        bhi[nt][kk][j] = (short)hh;
        blo[nt][kk][j] = (short)f2bf(w - bf2f(hh));
      }

  const int ngroups = (n + 31) >> 5;
  for (int g = blockIdx.x; g < ngroups; g += GEMM_BLOCKS) {
    const int base = g * 32 + tile * 16;
    const int row = base + i16;
    const int rowc = (row < n) ? row : (n - 1);
    const float* xp = x + (size_t)rowc * CH + kseg * 8;

    float af[16];
    {
      const float4 p0 = *(const float4*)(xp);
      const float4 p1 = *(const float4*)(xp + 4);
      const float4 q0 = *(const float4*)(xp + 32);
      const float4 q1 = *(const float4*)(xp + 36);
      af[0] = p0.x; af[1] = p0.y; af[2] = p0.z; af[3] = p0.w;
      af[4] = p1.x; af[5] = p1.y; af[6] = p1.z; af[7] = p1.w;
      af[8] = q0.x; af[9] = q0.y; af[10] = q0.z; af[11] = q0.w;
      af[12] = q1.x; af[13] = q1.y; af[14] = q1.z; af[15] = q1.w;
    }
    short8 ahi[2], alo[2];
#pragma unroll
    for (int kk = 0; kk < 2; ++kk)
#pragma unroll
      for (int j = 0; j < 8; ++j) {
        const float f = af[kk * 8 + j];
        const unsigned short hh = f2bf(f);
        ahi[kk][j] = (short)hh;
        alo[kk][j] = (short)f2bf(f - bf2f(hh));
      }

    f32x4 acc[4];
#pragma unroll
    for (int nt = 0; nt < 4; ++nt) {
      f32x4 a = {0.f, 0.f, 0.f, 0.f};
#pragma unroll
      for (int kk = 0; kk < 2; ++kk) {
        a = __builtin_amdgcn_mfma_f32_16x16x32_bf16(ahi[kk], bhi[nt][kk], a, 0, 0, 0);
        a = __builtin_amdgcn_mfma_f32_16x16x32_bf16(alo[kk], bhi[nt][kk], a, 0, 0, 0);
        a = __builtin_amdgcn_mfma_f32_16x16x32_bf16(ahi[kk], blo[nt][kk], a, 0, 0, 0);
      }
      acc[nt] = a;
    }

    if (mat == 0) {
#pragma unroll
      for (int nt = 0; nt < 4; ++nt)
#pragma unroll
        for (int r = 0; r < 4; ++r) {
          const int orow = base + kseg * 4 + r;
          if (orow < n)
            xwb[(size_t)orow * CH + nt * 16 + i16] = f2bf(acc[nt][r]);
        }
    } else {
#pragma unroll
      for (int nt = 0; nt < 4; ++nt)
#pragma unroll
        for (int r = 0; r < 4; ++r) {
          const int orow = base + kseg * 4 + r;
          if (orow < n)
            out[(size_t)orow * CH + nt * 16 + i16] = acc[nt][r];
        }
    }
  }
}

// ---------------------------------------------------------------------------
// Phase B: exclusive scan of countsT (length nb*NBLK), in place, 3 kernels.
// ---------------------------------------------------------------------------
__global__ __launch_bounds__(SCAN_B) void scan_partial(
    const int* __restrict__ in, int* __restrict__ partials, int n) {
  __shared__ int s[SCAN_B];
  const int i = blockIdx.x * SCAN_B + threadIdx.x;
  s[threadIdx.x] = (i < n) ? in[i] : 0;
  __syncthreads();
  for (int off = SCAN_B / 2; off > 0; off >>= 1) {
    if (threadIdx.x < off) s[threadIdx.x] += s[threadIdx.x + off];
    __syncthreads();
  }
  if (threadIdx.x == 0) partials[blockIdx.x] = s[0];
}

__global__ __launch_bounds__(1024) void scan_partials_scan(
    int* __restrict__ partials, int nb) {
  __shared__ int s[1024];
  const int v = (threadIdx.x < nb) ? partials[threadIdx.x] : 0;
  s[threadIdx.x] = v;
  __syncthreads();
  for (int off = 1; off < 1024; off <<= 1) {
    const int t = (threadIdx.x >= off) ? s[threadIdx.x - off] : 0;
    __syncthreads();
    s[threadIdx.x] += t;
    __syncthreads();
  }
  if (threadIdx.x < nb) partials[threadIdx.x] = s[threadIdx.x] - v;  // exclusive
}

__global__ __launch_bounds__(SCAN_B) void scan_final(
    int* __restrict__ data, const int* __restrict__ partials, int n) {
  __shared__ int s[SCAN_B];
  const int i = blockIdx.x * SCAN_B + threadIdx.x;
  const int v = (i < n) ? data[i] : 0;
  s[threadIdx.x] = v;
  __syncthreads();
  for (int off = 1; off < SCAN_B; off <<= 1) {
    const int t = (threadIdx.x >= off) ? s[threadIdx.x - off] : 0;
    __syncthreads();
    s[threadIdx.x] += t;
    __syncthreads();
  }
  if (i < n) data[i] = s[threadIdx.x] - v + partials[blockIdx.x];  // exclusive
}

// ---------------------------------------------------------------------------
// Phase C: fill bucketed edge records. LDS cursors only. 1024 thr (16 waves).
// record.x = ((row & 127) << 17) | col,  record.y = val bits
// ---------------------------------------------------------------------------
__global__ __launch_bounds__(1024) void fillB_kernel(
    const int* __restrict__ r1, const int* __restrict__ c1, const float* __restrict__ v1,
    const int* __restrict__ r2, const int* __restrict__ c2, const float* __restrict__ v2,
    const int* __restrict__ soff, int2* __restrict__ ebuf, int nnz, int nb) {
  __shared__ int cur[MAXNB];
  for (int b = threadIdx.x; b < nb; b += 1024)
    cur[b] = soff[b * NBLK + blockIdx.x];
  __syncthreads();
  const int tot = 2 * nnz;
  const int chunk = (tot + NBLK - 1) / NBLK;
  const int e0 = blockIdx.x * chunk;
  const int e1 = min(tot, e0 + chunk);
  for (int e = e0 + threadIdx.x; e < e1; e += 1024) {
    int r, c;
    float v;
    if (e < nnz) {
      r = r1[e]; c = c1[e]; v = v1[e];
    } else {
      r = r2[e - nnz]; c = c2[e - nnz]; v = v2[e - nnz];
    }
    const int b = r >> RPB_SH;
    const int slot = atomicAdd(&cur[b], 1);
    ebuf[slot] = make_int2(((r & (RPB - 1)) << 17) | c, __float_as_int(v));
  }
}

// ---------------------------------------------------------------------------
// Phase D: in-bucket counting sort (one block per bucket). 512 thr, 36 KB LDS
// -> 4 blocks/CU. Emits row_ptr.
// ---------------------------------------------------------------------------
__global__ __launch_bounds__(512) void sortB_kernel(
    const int* __restrict__ soff, int2* __restrict__ ebuf,
    int* __restrict__ row_ptr, int* __restrict__ bflag,
    int n, int nb, int tot) {
  __shared__ int2 raw[CAP];   // 36 KB
  __shared__ int hist[RPB];
  __shared__ int sc[RPB];
  __shared__ int cur[RPB];
  const int b = blockIdx.x;
  const int beg = soff[b * NBLK];
  const int end = (b + 1 < nb) ? soff[(b + 1) * NBLK] : tot;
  const int cnt = end - beg;

  if (b == nb - 1 && threadIdx.x == 0) row_ptr[n] = tot;

  if (cnt > CAP) {  // degenerate distribution: leave unsorted, flag for gather
    if (threadIdx.x == 0) bflag[b] = 1;
    const int r0 = b * RPB;
    for (int r = threadIdx.x; r < RPB; r += 512) {
      const int gr = r0 + r;
      if (gr < n) row_ptr[gr] = beg;
    }
    return;
  }
  if (threadIdx.x == 0) bflag[b] = 0;
  if (threadIdx.x < RPB) hist[threadIdx.x] = 0;
  __syncthreads();

  for (int i = threadIdx.x; i < cnt; i += 512) {
    const int2 rec = ebuf[beg + i];
    raw[i] = rec;
    atomicAdd(&hist[rec.x >> 17], 1);
  }
  __syncthreads();

  int v = 0;
  if (threadIdx.x < RPB) {
    v = hist[threadIdx.x];
    sc[threadIdx.x] = v;
  }
  __syncthreads();
  for (int off = 1; off < RPB; off <<= 1) {
    int t = 0;
    if (threadIdx.x < RPB && threadIdx.x >= off) t = sc[threadIdx.x - off];
    __syncthreads();
    if (threadIdx.x < RPB) sc[threadIdx.x] += t;
    __syncthreads();
  }
  if (threadIdx.x < RPB) {
    const int ex = sc[threadIdx.x] - v;
    cur[threadIdx.x] = ex;
    const int gr = b * RPB + threadIdx.x;
    if (gr < n) row_ptr[gr] = beg + ex;
  }
  __syncthreads();

  for (int i = threadIdx.x; i < cnt; i += 512) {
    const int2 rec = raw[i];
    const int pos = atomicAdd(&cur[rec.x >> 17], 1);
    ebuf[beg + pos] = rec;
  }
}

// ---------------------------------------------------------------------------
// Phase E: row gather — half-wave dual-edge, software-pipelined record loads.
// ---------------------------------------------------------------------------
__global__ __launch_bounds__(256) void gather_kernel(
    const int* __restrict__ row_ptr, const int* __restrict__ soff,
    const int* __restrict__ bflag, const int2* __restrict__ ebuf,
    const unsigned int* __restrict__ xw32, float2* __restrict__ out2,
    int n, int nb, int tot) {
  const int lane = threadIdx.x & 63;
  const int half = lane >> 5;
  const int l32 = lane & 31;
  const int w = (blockIdx.x * blockDim.x + threadIdx.x) >> 6;
  const int nw = (gridDim.x * blockDim.x) >> 6;

  for (int row = w; row < n; row += nw) {
    float2 acc;
    if (half == 0) acc = out2[(size_t)row * 32 + l32];  // linear term
    else acc = make_float2(0.f, 0.f);

    const int b = row >> RPB_SH;
    if (bflag[b]) {  // degenerate fallback
      const int bb = soff[b * NBLK];
      const int be = (b + 1 < nb) ? soff[(b + 1) * NBLK] : tot;
      const int rl = row & (RPB - 1);
      for (int e = bb; e < be; ++e) {
        const int2 rec = ebuf[e];
        if ((rec.x >> 17) == rl && half == 0) {
          const unsigned int u = xw32[(size_t)(rec.x & 0x1FFFF) * 32 + l32];
          const float v = __int_as_float(rec.y);
          acc.x = fmaf(v, __uint_as_float(u << 16), acc.x);
          acc.y = fmaf(v, __uint_as_float(u & 0xFFFF0000u), acc.y);
        }
      }
    } else {
      const int beg = row_ptr[row];
      const int end = row_ptr[row + 1];
      int e = beg;
      if (e + 16 <= end) {
        int2 rc[8];
#pragma unroll
        for (int j = 0; j < 8; ++j) rc[j] = ebuf[e + 2 * j + half];
        while (true) {
          unsigned int u[8];
#pragma unroll
          for (int j = 0; j < 8; ++j)
            u[j] = xw32[(size_t)(rc[j].x & 0x1FFFF) * 32 + l32];
          const int en = e + 16;
          const bool more = (en + 16 <= end);
          int2 rcn[8];
          if (more) {
#pragma unroll
            for (int j = 0; j < 8; ++j) rcn[j] = ebuf[en + 2 * j + half];
          }
#pragma unroll
          for (int j = 0; j < 8; ++j) {
            const float v = __int_as_float(rc[j].y);
            acc.x = fmaf(v, __uint_as_float(u[j] << 16), acc.x);
            acc.y = fmaf(v, __uint_as_float(u[j] & 0xFFFF0000u), acc.y);
          }
          e = en;
          if (!more) break;
#pragma unroll
          for (int j = 0; j < 8; ++j) rc[j] = rcn[j];
        }
      }
      for (; e < end; e += 2) {
        const int idx = e + half;
        const bool ok = idx < end;
        const int2 rc = ebuf[ok ? idx : (end - 1)];
        const unsigned int u = xw32[(size_t)(rc.x & 0x1FFFF) * 32 + l32];
        const float v = ok ? __int_as_float(rc.y) : 0.f;
        acc.x = fmaf(v, __uint_as_float(u << 16), acc.x);
        acc.y = fmaf(v, __uint_as_float(u & 0xFFFF0000u), acc.y);
      }
    }

    acc.x += __shfl_xor(acc.x, 32, 64);
    acc.y += __shfl_xor(acc.y, 32, 64);
    if (half == 0) {
      acc.x = 1.f / (1.f + __expf(-acc.x));
      acc.y = 1.f / (1.f + __expf(-acc.y));
      out2[(size_t)row * 32 + l32] = acc;
    }
  }
}

// ---------------------------------------------------------------------------
// Fallback path (ws too small): atomic scatter + sigmoid.
// ---------------------------------------------------------------------------
__global__ __launch_bounds__(256) void scatter_kernel(
    const int* __restrict__ rows, const int* __restrict__ cols,
    const float* __restrict__ vals, const unsigned short* __restrict__ xwb,
    float* __restrict__ out, int nnz) {
  const int lane = threadIdx.x & 63;
  const int wid = (blockIdx.x * blockDim.x + threadIdx.x) >> 6;
  const int nwaves = (gridDim.x * blockDim.x) >> 6;
  for (int k = wid; k < nnz; k += nwaves) {
    const float xv = bf2f(xwb[(size_t)cols[k] * CH + lane]);
    atomicAdd(&out[(size_t)rows[k] * CH + lane], vals[k] * xv);
  }
}

__global__ __launch_bounds__(256) void sigmoid_kernel(float* __restrict__ out, int n4) {
  const int i = blockIdx.x * blockDim.x + threadIdx.x;
  if (i < n4) {
    float4 v = reinterpret_cast<float4*>(out)[i];
    v.x = 1.f / (1.f + __expf(-v.x));
    v.y = 1.f / (1.f + __expf(-v.y));
    v.z = 1.f / (1.f + __expf(-v.z));
    v.w = 1.f / (1.f + __expf(-v.w));
    reinterpret_cast<float4*>(out)[i] = v;
  }
}

extern "C" void kernel_launch(void* const* d_in, const int* in_sizes, int n_in,
                              void* d_out, int out_size, void* d_ws, size_t ws_size,
                              hipStream_t stream) {
  const float* x         = (const float*)d_in[0];
  const int*   down_rows = (const int*)d_in[1];
  const int*   down_cols = (const int*)d_in[2];
  const float* down_vals = (const float*)d_in[3];
  const int*   up_rows   = (const int*)d_in[4];
  const int*   up_cols   = (const int*)d_in[5];
  const float* up_vals   = (const float*)d_in[6];
  const float* w_conv    = (const float*)d_in[7];
  const float* w_lin     = (const float*)d_in[8];

  const int n   = in_sizes[0] / CH;  // 100000
  const int nnz = in_sizes[1];       // 1600000
  const int tot = 2 * nnz;
  const int nb  = (n + RPB - 1) / RPB;  // 782

  float* out = (float*)d_out;

  // ws layout (xw stored as bf16)
  char* p = (char*)d_ws;
  unsigned short* xwb = (unsigned short*)p;  p += (size_t)n * CH * 2;
  int* soff    = (int*)p;  p += (size_t)nb * NBLK * 4;
  int* partial = (int*)p;  p += 1024 * 4;
  int* row_ptr = (int*)p;  p += ((size_t)n + 2) * 4;
  int* bflag   = (int*)p;  p += (size_t)nb * 4;
  p = (char*)(((uintptr_t)p + 7) & ~(uintptr_t)7);
  int2* ebuf   = (int2*)p; p += (size_t)tot * 8;
  const size_t need = (size_t)(p - (char*)d_ws);

  if (ws_size >= need && nb <= MAXNB && n < (1 << 17)) {
    // GEMM (blocks 0..1023) + countT (blocks 1024..1279) in one launch
    gemm_count_kernel<<<GEMM_BLOCKS + NBLK, 256, 0, stream>>>(
        x, w_conv, w_lin, xwb, out, n, down_rows, up_rows, soff, nnz, nb);
    const int ntot = nb * NBLK;
    const int nsb = (ntot + SCAN_B - 1) / SCAN_B;  // 391 <= 1024
    scan_partial<<<nsb, SCAN_B, 0, stream>>>(soff, partial, ntot);
    scan_partials_scan<<<1, 1024, 0, stream>>>(partial, nsb);
    scan_final<<<nsb, SCAN_B, 0, stream>>>(soff, partial, ntot);
    fillB_kernel<<<NBLK, 1024, 0, stream>>>(down_rows, down_cols, down_vals,
                                            up_rows, up_cols, up_vals,
                                            soff, ebuf, nnz, nb);
    sortB_kernel<<<nb, 512, 0, stream>>>(soff, ebuf, row_ptr, bflag, n, nb, tot);
    const int nblk = (n + 3) / 4;
    gather_kernel<<<nblk, 256, 0, stream>>>(row_ptr, soff, bflag, ebuf,
                                            (const unsigned int*)xwb,
                                            (float2*)out, n, nb, tot);
  } else {
    // fallback: gemm only (nb=0 disables count work; countsT ptr unused)
    gemm_count_kernel<<<GEMM_BLOCKS, 256, 0, stream>>>(
        x, w_conv, w_lin, xwb, out, n, down_rows, up_rows, (int*)d_ws, nnz, 0);
    scatter_kernel<<<4096, 256, 0, stream>>>(down_rows, down_cols, down_vals, xwb, out, nnz);
    scatter_kernel<<<4096, 256, 0, stream>>>(up_rows, up_cols, up_vals, xwb, out, nnz);
    const int n4 = (n * CH) / 4;
    sigmoid_kernel<<<(n4 + 255) / 256, 256, 0, stream>>>(out, n4);
  }
}